// Round 1
// baseline (402.941 us; speedup 1.0000x reference)
//
#include <hip/hip_runtime.h>

#define N_NODES   50000
#define N_EDGES   1600000
#define N_FEAT    512
#define N_HID     128
#define NUM_GRAPHS 128
#define SCAN_BLOCKS 196   // ceil(50000/256)

static __device__ __forceinline__ unsigned short f2bf(float f) {
  union { float f; unsigned int u; } v; v.f = f;
  unsigned int u = v.u;
  unsigned int r = (u + 0x7FFFu + ((u >> 16) & 1u)) >> 16;   // RNE
  return (unsigned short)r;
}
static __device__ __forceinline__ float bf2f(unsigned int bits16) {
  union { unsigned int u; float f; } v; v.u = bits16 << 16; return v.f;
}

// ---------------- init: zero cnt / cursor / pooled ----------------
__global__ void init_ws(int* __restrict__ cnt, int* __restrict__ cursor,
                        int* __restrict__ pooled) {
  int i = blockIdx.x * 256 + threadIdx.x;
  if (i < N_NODES) { cnt[i] = 0; cursor[i] = 0; }
  if (i < NUM_GRAPHS * N_HID) pooled[i] = 0;
}

// ---------------- degree count over dst ----------------
__global__ void count_deg(const int* __restrict__ edge, int* __restrict__ cnt) {
  int e = blockIdx.x * 256 + threadIdx.x;
  if (e < N_EDGES) atomicAdd(&cnt[edge[N_EDGES + e]], 1);
}

// ---------------- dinv = rsqrt(deg), deg = cnt + 1 (self loop) ----------------
__global__ void dinv_kernel(const int* __restrict__ cnt, float* __restrict__ dinv) {
  int i = blockIdx.x * 256 + threadIdx.x;
  if (i < N_NODES) dinv[i] = rsqrtf((float)(cnt[i] + 1));
}

// ---------------- 3-kernel exclusive scan of cnt -> offs ----------------
__global__ void scan1(const int* __restrict__ cnt, int* __restrict__ offs,
                      int* __restrict__ bsum) {
  __shared__ int s[256];
  int t = threadIdx.x;
  int i = blockIdx.x * 256 + t;
  int v = (i < N_NODES) ? cnt[i] : 0;
  s[t] = v;
  __syncthreads();
  for (int d = 1; d < 256; d <<= 1) {
    int add = (t >= d) ? s[t - d] : 0;
    __syncthreads();
    s[t] += add;
    __syncthreads();
  }
  if (i < N_NODES) offs[i] = s[t] - v;           // exclusive within block
  if (t == 255) bsum[blockIdx.x] = s[255];
}
__global__ void scan2(int* __restrict__ bsum) {    // single block, 256 threads
  __shared__ int s[256];
  int t = threadIdx.x;
  int v = (t < SCAN_BLOCKS) ? bsum[t] : 0;
  s[t] = v;
  __syncthreads();
  for (int d = 1; d < 256; d <<= 1) {
    int add = (t >= d) ? s[t - d] : 0;
    __syncthreads();
    s[t] += add;
    __syncthreads();
  }
  if (t < SCAN_BLOCKS) bsum[t] = s[t] - v;        // exclusive block offsets
}
__global__ void scan3(int* __restrict__ offs, const int* __restrict__ bsum) {
  int i = blockIdx.x * 256 + threadIdx.x;
  if (i < N_NODES) offs[i] += bsum[blockIdx.x];
}

// ---------------- GEMM: h(bf16)[N,128] = x[N,512] @ W1[512,128] ----------------
// block: 256 threads; tile 64 rows x 128 cols; K-chunk 32.
// thread t: tx = t&31 -> cols tx*4..tx*4+3 ; ty = t>>5 -> rows ty*8..ty*8+7
__global__ __launch_bounds__(256) void gemm_xw(const float* __restrict__ x,
                                               const float* __restrict__ W,
                                               unsigned short* __restrict__ h) {
  __shared__ float sX[32][68];    // transposed x tile: sX[k][row], +4 pad
  __shared__ float sW[32][128];   // sW[k][col]
  const int t = threadIdx.x;
  const int tx = t & 31, ty = t >> 5;
  const int block_row = blockIdx.x * 64;

  float acc[8][4];
#pragma unroll
  for (int r = 0; r < 8; r++)
#pragma unroll
    for (int c = 0; c < 4; c++) acc[r][c] = 0.f;

  const int lr = t >> 3;          // 0..31
  const int lk = (t & 7) * 4;     // 0,4,..,28

  for (int k0 = 0; k0 < N_FEAT; k0 += 32) {
    // load x tile (64 rows x 32 k), transposed into LDS
    int r0 = block_row + lr;      if (r0 >= N_NODES) r0 = N_NODES - 1;
    int r1 = block_row + lr + 32; if (r1 >= N_NODES) r1 = N_NODES - 1;
    float4 v0 = *(const float4*)(x + (size_t)r0 * N_FEAT + k0 + lk);
    float4 v1 = *(const float4*)(x + (size_t)r1 * N_FEAT + k0 + lk);
    sX[lk + 0][lr] = v0.x; sX[lk + 1][lr] = v0.y;
    sX[lk + 2][lr] = v0.z; sX[lk + 3][lr] = v0.w;
    sX[lk + 0][lr + 32] = v1.x; sX[lk + 1][lr + 32] = v1.y;
    sX[lk + 2][lr + 32] = v1.z; sX[lk + 3][lr + 32] = v1.w;
    // load W tile (32 k x 128 cols), contiguous
    {
      const float4* wsrc = (const float4*)(W + (size_t)k0 * N_HID);
      float4* wdst = (float4*)(&sW[0][0]);
#pragma unroll
      for (int i = 0; i < 4; i++) wdst[t + 256 * i] = wsrc[t + 256 * i];
    }
    __syncthreads();

#pragma unroll 8
    for (int k = 0; k < 32; k++) {
      const float4 xa = *(const float4*)(&sX[k][ty * 8]);
      const float4 xb = *(const float4*)(&sX[k][ty * 8 + 4]);
      const float4 wv = *(const float4*)(&sW[k][tx * 4]);
      float xr[8] = {xa.x, xa.y, xa.z, xa.w, xb.x, xb.y, xb.z, xb.w};
      float wc[4] = {wv.x, wv.y, wv.z, wv.w};
#pragma unroll
      for (int r = 0; r < 8; r++)
#pragma unroll
        for (int c = 0; c < 4; c++)
          acc[r][c] = fmaf(xr[r], wc[c], acc[r][c]);
    }
    __syncthreads();
  }

#pragma unroll
  for (int rr = 0; rr < 8; rr++) {
    int row = block_row + ty * 8 + rr;
    if (row < N_NODES) {
      ushort4 hv;
      hv.x = f2bf(acc[rr][0]); hv.y = f2bf(acc[rr][1]);
      hv.z = f2bf(acc[rr][2]); hv.w = f2bf(acc[rr][3]);
      *(ushort4*)(h + (size_t)row * N_HID + tx * 4) = hv;
    }
  }
}

// ---------------- scatter edges into dst-sorted bins ----------------
__global__ void scatter_edges(const int* __restrict__ edge,
                              const float* __restrict__ dinv,
                              const int* __restrict__ offs,
                              int* __restrict__ cursor,
                              int2* __restrict__ sedge) {
  int e = blockIdx.x * 256 + threadIdx.x;
  if (e < N_EDGES) {
    int s = edge[e];
    int d = edge[N_EDGES + e];
    int pos = offs[d] + atomicAdd(&cursor[d], 1);
    int2 ew;
    ew.x = s;
    ew.y = __float_as_int(dinv[s] * dinv[d]);
    sedge[pos] = ew;
  }
}

// ---------------- aggregation + bias + relu + fused segment-max pool ----------------
// 256 threads = 4 nodes x 64 lanes; each lane owns 2 features (bf16x2 load)
__global__ __launch_bounds__(256) void aggregate_pool(
    const unsigned short* __restrict__ h, const int2* __restrict__ sedge,
    const float* __restrict__ dinv, const int* __restrict__ cnt,
    const int* __restrict__ offs, const float* __restrict__ b1,
    const int* __restrict__ batch, int* __restrict__ pooled) {
  int node = blockIdx.x * 4 + (threadIdx.x >> 6);
  int lane = threadIdx.x & 63;
  int f2 = lane * 2;

  float dv = dinv[node];
  unsigned int p = *(const unsigned int*)(h + (size_t)node * N_HID + f2);
  float a0 = bf2f(p & 0xFFFFu) * dv * dv;   // self loop
  float a1 = bf2f(p >> 16) * dv * dv;

  int base = offs[node];
  int n = cnt[node];
#pragma unroll 4
  for (int j = 0; j < n; j++) {
    int2 ew = sedge[base + j];
    float w = __int_as_float(ew.y);
    unsigned int q = *(const unsigned int*)(h + (size_t)ew.x * N_HID + f2);
    a0 = fmaf(w, bf2f(q & 0xFFFFu), a0);
    a1 = fmaf(w, bf2f(q >> 16), a1);
  }
  a0 = fmaxf(a0 + b1[f2], 0.f);
  a1 = fmaxf(a1 + b1[f2 + 1], 0.f);

  int g = batch[node];
  atomicMax(&pooled[g * N_HID + f2],     __float_as_int(a0));
  atomicMax(&pooled[g * N_HID + f2 + 1], __float_as_int(a1));
}

// ---------------- head: logits + log_softmax ----------------
__global__ __launch_bounds__(128) void head_kernel(const int* __restrict__ pooled,
                                                   const float* __restrict__ W2,
                                                   const float* __restrict__ b2,
                                                   float* __restrict__ out) {
  __shared__ float sW[N_HID * 2];
  int t = threadIdx.x;
  sW[t] = W2[t];
  sW[t + 128] = W2[t + 128];
  __syncthreads();
  float l0 = b2[0], l1 = b2[1];
  for (int f = 0; f < N_HID; f++) {
    float pv = __int_as_float(pooled[t * N_HID + f]);
    l0 = fmaf(pv, sW[f * 2 + 0], l0);
    l1 = fmaf(pv, sW[f * 2 + 1], l1);
  }
  float m = fmaxf(l0, l1);
  float lse = m + logf(expf(l0 - m) + expf(l1 - m));
  out[t * 2 + 0] = l0 - lse;
  out[t * 2 + 1] = l1 - lse;
}

extern "C" void kernel_launch(void* const* d_in, const int* in_sizes, int n_in,
                              void* d_out, int out_size, void* d_ws, size_t ws_size,
                              hipStream_t stream) {
  const float* x   = (const float*)d_in[0];
  const float* W1  = (const float*)d_in[1];
  const float* b1  = (const float*)d_in[2];
  const float* W2  = (const float*)d_in[3];
  const float* b2  = (const float*)d_in[4];
  const int* edge  = (const int*)d_in[5];
  const int* batch = (const int*)d_in[6];
  float* out = (float*)d_out;

  char* ws = (char*)d_ws;
  // workspace layout (256-aligned)
  int*   cnt    = (int*)(ws + 0);          // 50000 ints
  int*   cursor = (int*)(ws + 200192);     // 50000 ints
  int*   offs   = (int*)(ws + 400384);     // 50000 ints
  int*   bsum   = (int*)(ws + 600576);     // 256 ints
  float* dinv   = (float*)(ws + 601600);   // 50000 f32
  int*   pooled = (int*)(ws + 801792);     // 128*128 ints
  int2*  sedge  = (int2*)(ws + 867328);    // 1.6M int2 (12.8 MB)
  unsigned short* h = (unsigned short*)(ws + 13667328); // 50000*128 bf16 (12.8 MB)

  init_ws<<<SCAN_BLOCKS, 256, 0, stream>>>(cnt, cursor, pooled);
  count_deg<<<N_EDGES / 256, 256, 0, stream>>>(edge, cnt);
  dinv_kernel<<<SCAN_BLOCKS, 256, 0, stream>>>(cnt, dinv);
  scan1<<<SCAN_BLOCKS, 256, 0, stream>>>(cnt, offs, bsum);
  scan2<<<1, 256, 0, stream>>>(bsum);
  scan3<<<SCAN_BLOCKS, 256, 0, stream>>>(offs, bsum);
  gemm_xw<<<(N_NODES + 63) / 64, 256, 0, stream>>>(x, W1, h);
  scatter_edges<<<N_EDGES / 256, 256, 0, stream>>>(edge, dinv, offs, cursor, sedge);
  aggregate_pool<<<N_NODES / 4, 256, 0, stream>>>(h, sedge, dinv, cnt, offs, b1, batch, pooled);
  head_kernel<<<1, 128, 0, stream>>>(pooled, W2, b2, out);
}

// Round 2
// 367.631 us; speedup vs baseline: 1.0960x; 1.0960x over previous
//
#include <hip/hip_runtime.h>

#define N_NODES   50000
#define N_EDGES   1600000
#define N_FEAT    512
#define N_HID     128
#define NUM_GRAPHS 128
#define SCAN_BLOCKS 196   // ceil(50000/256)
#define N_WAVES_GEMM (N_NODES / 16)   // 3125

typedef short bf16x8 __attribute__((ext_vector_type(8)));
typedef float f32x4  __attribute__((ext_vector_type(4)));

static __device__ __forceinline__ unsigned short f2bf(float f) {
  union { float f; unsigned int u; } v; v.f = f;
  unsigned int u = v.u;
  unsigned int r = (u + 0x7FFFu + ((u >> 16) & 1u)) >> 16;   // RNE
  return (unsigned short)r;
}
static __device__ __forceinline__ float bf2f(unsigned int bits16) {
  union { unsigned int u; float f; } v; v.u = bits16 << 16; return v.f;
}

// ---------------- init: zero cnt / cursor / pooled ----------------
__global__ void init_ws(int* __restrict__ cnt, int* __restrict__ cursor,
                        int* __restrict__ pooled) {
  int i = blockIdx.x * 256 + threadIdx.x;
  if (i < N_NODES) { cnt[i] = 0; cursor[i] = 0; }
  if (i < NUM_GRAPHS * N_HID) pooled[i] = 0;
}

// ---------------- degree count over dst ----------------
__global__ void count_deg(const int* __restrict__ edge, int* __restrict__ cnt) {
  int e = blockIdx.x * 256 + threadIdx.x;
  if (e < N_EDGES) atomicAdd(&cnt[edge[N_EDGES + e]], 1);
}

// ---------------- dinv = rsqrt(deg), deg = cnt + 1 (self loop) ----------------
__global__ void dinv_kernel(const int* __restrict__ cnt, float* __restrict__ dinv) {
  int i = blockIdx.x * 256 + threadIdx.x;
  if (i < N_NODES) dinv[i] = rsqrtf((float)(cnt[i] + 1));
}

// ---------------- 3-kernel exclusive scan of cnt -> offs ----------------
__global__ void scan1(const int* __restrict__ cnt, int* __restrict__ offs,
                      int* __restrict__ bsum) {
  __shared__ int s[256];
  int t = threadIdx.x;
  int i = blockIdx.x * 256 + t;
  int v = (i < N_NODES) ? cnt[i] : 0;
  s[t] = v;
  __syncthreads();
  for (int d = 1; d < 256; d <<= 1) {
    int add = (t >= d) ? s[t - d] : 0;
    __syncthreads();
    s[t] += add;
    __syncthreads();
  }
  if (i < N_NODES) offs[i] = s[t] - v;           // exclusive within block
  if (t == 255) bsum[blockIdx.x] = s[255];
}
__global__ void scan2(int* __restrict__ bsum) {    // single block, 256 threads
  __shared__ int s[256];
  int t = threadIdx.x;
  int v = (t < SCAN_BLOCKS) ? bsum[t] : 0;
  s[t] = v;
  __syncthreads();
  for (int d = 1; d < 256; d <<= 1) {
    int add = (t >= d) ? s[t - d] : 0;
    __syncthreads();
    s[t] += add;
    __syncthreads();
  }
  if (t < SCAN_BLOCKS) bsum[t] = s[t] - v;        // exclusive block offsets
}
__global__ void scan3(int* __restrict__ offs, const int* __restrict__ bsum) {
  int i = blockIdx.x * 256 + threadIdx.x;
  if (i < N_NODES) offs[i] += bsum[blockIdx.x];
}

// ---------------- W1 [512][128] fp32 -> wT [128][512] bf16 ----------------
__global__ __launch_bounds__(256) void wconv(const float* __restrict__ W,
                                             unsigned short* __restrict__ wT) {
  int i = blockIdx.x * 256 + threadIdx.x;
  if (i < N_HID * N_FEAT) {
    int n = i >> 9, k = i & 511;
    wT[i] = f2bf(W[(size_t)k * N_HID + n]);
  }
}

// ---------------- GEMM: h(bf16)[N,128] = x[N,512] @ W1 via MFMA bf16 ----------------
// 1 wave = 16 rows x 128 cols. No LDS. A from global x (each elem read once,
// coalesced); B frags from L2-resident wT. 8x mfma_f32_16x16x32_bf16 per K-step.
__global__ __launch_bounds__(256) void gemm_mfma(const float* __restrict__ x,
                                                 const unsigned short* __restrict__ wT,
                                                 unsigned short* __restrict__ h) {
  const int wave = (blockIdx.x * 256 + threadIdx.x) >> 6;
  if (wave >= N_WAVES_GEMM) return;          // wave-uniform guard
  const int lane = threadIdx.x & 63;
  const int row0 = wave * 16;
  const int arow = row0 + (lane & 15);
  const int kbase = (lane >> 4) * 8;         // contiguous-8 K per lane (m92 layout)

  f32x4 acc[8];
#pragma unroll
  for (int i = 0; i < 8; i++) acc[i] = (f32x4){0.f, 0.f, 0.f, 0.f};

  for (int k0 = 0; k0 < N_FEAT; k0 += 32) {
    // A fragment: x[arow][k0+kbase .. +7] fp32 -> bf16
    const float* ap = x + (size_t)arow * N_FEAT + k0 + kbase;
    float4 a0 = *(const float4*)ap;
    float4 a1 = *(const float4*)(ap + 4);
    bf16x8 af;
    af[0] = (short)f2bf(a0.x); af[1] = (short)f2bf(a0.y);
    af[2] = (short)f2bf(a0.z); af[3] = (short)f2bf(a0.w);
    af[4] = (short)f2bf(a1.x); af[5] = (short)f2bf(a1.y);
    af[6] = (short)f2bf(a1.z); af[7] = (short)f2bf(a1.w);

#pragma unroll
    for (int ct = 0; ct < 8; ct++) {
      const bf16x8 bf = *(const bf16x8*)(wT + (size_t)(ct * 16 + (lane & 15)) * N_FEAT
                                            + k0 + kbase);
      acc[ct] = __builtin_amdgcn_mfma_f32_16x16x32_bf16(af, bf, acc[ct], 0, 0, 0);
    }
  }

  // C/D layout: col = lane&15, row = (lane>>4)*4 + reg   [m89]
#pragma unroll
  for (int ct = 0; ct < 8; ct++) {
#pragma unroll
    for (int r = 0; r < 4; r++) {
      int row = row0 + (lane >> 4) * 4 + r;
      int col = ct * 16 + (lane & 15);
      h[(size_t)row * N_HID + col] = f2bf(acc[ct][r]);
    }
  }
}

// ---------------- scatter edges into dst-sorted bins ----------------
__global__ void scatter_edges(const int* __restrict__ edge,
                              const float* __restrict__ dinv,
                              const int* __restrict__ offs,
                              int* __restrict__ cursor,
                              int2* __restrict__ sedge) {
  int e = blockIdx.x * 256 + threadIdx.x;
  if (e < N_EDGES) {
    int s = edge[e];
    int d = edge[N_EDGES + e];
    int pos = offs[d] + atomicAdd(&cursor[d], 1);
    int2 ew;
    ew.x = s;
    ew.y = __float_as_int(dinv[s] * dinv[d]);
    sedge[pos] = ew;
  }
}

// ---------------- aggregation + bias + relu + fused segment-max pool ----------------
// 256 threads = 4 nodes x 64 lanes; each lane owns 2 features.
// 8-deep software pipeline: batch sedge loads, then batch gathers, then FMAs.
__global__ __launch_bounds__(256) void aggregate_pool(
    const unsigned short* __restrict__ h, const int2* __restrict__ sedge,
    const float* __restrict__ dinv, const int* __restrict__ cnt,
    const int* __restrict__ offs, const float* __restrict__ b1,
    const int* __restrict__ batch, int* __restrict__ pooled) {
  int node = blockIdx.x * 4 + (threadIdx.x >> 6);
  int lane = threadIdx.x & 63;
  int f2 = lane * 2;

  float dv = dinv[node];
  unsigned int p = *(const unsigned int*)(h + (size_t)node * N_HID + f2);
  float a0 = bf2f(p & 0xFFFFu) * dv * dv;   // self loop
  float a1 = bf2f(p >> 16) * dv * dv;

  const int base = offs[node];
  const int n = cnt[node];
  const int n8 = n & ~7;
  int j = 0;
  for (; j < n8; j += 8) {
    int2 e[8];
#pragma unroll
    for (int u = 0; u < 8; u++) e[u] = sedge[base + j + u];
    unsigned int q[8];
#pragma unroll
    for (int u = 0; u < 8; u++)
      q[u] = *(const unsigned int*)(h + (size_t)e[u].x * N_HID + f2);
#pragma unroll
    for (int u = 0; u < 8; u++) {
      float w = __int_as_float(e[u].y);
      a0 = fmaf(w, bf2f(q[u] & 0xFFFFu), a0);
      a1 = fmaf(w, bf2f(q[u] >> 16), a1);
    }
  }
  for (; j < n; j++) {
    int2 ew = sedge[base + j];
    float w = __int_as_float(ew.y);
    unsigned int q = *(const unsigned int*)(h + (size_t)ew.x * N_HID + f2);
    a0 = fmaf(w, bf2f(q & 0xFFFFu), a0);
    a1 = fmaf(w, bf2f(q >> 16), a1);
  }

  a0 = fmaxf(a0 + b1[f2], 0.f);
  a1 = fmaxf(a1 + b1[f2 + 1], 0.f);

  int g = batch[node];
  atomicMax(&pooled[g * N_HID + f2],     __float_as_int(a0));
  atomicMax(&pooled[g * N_HID + f2 + 1], __float_as_int(a1));
}

// ---------------- head: logits + log_softmax ----------------
__global__ __launch_bounds__(128) void head_kernel(const int* __restrict__ pooled,
                                                   const float* __restrict__ W2,
                                                   const float* __restrict__ b2,
                                                   float* __restrict__ out) {
  __shared__ float sW[N_HID * 2];
  int t = threadIdx.x;
  sW[t] = W2[t];
  sW[t + 128] = W2[t + 128];
  __syncthreads();
  float l0 = b2[0], l1 = b2[1];
  for (int f = 0; f < N_HID; f++) {
    float pv = __int_as_float(pooled[t * N_HID + f]);
    l0 = fmaf(pv, sW[f * 2 + 0], l0);
    l1 = fmaf(pv, sW[f * 2 + 1], l1);
  }
  float m = fmaxf(l0, l1);
  float lse = m + logf(expf(l0 - m) + expf(l1 - m));
  out[t * 2 + 0] = l0 - lse;
  out[t * 2 + 1] = l1 - lse;
}

extern "C" void kernel_launch(void* const* d_in, const int* in_sizes, int n_in,
                              void* d_out, int out_size, void* d_ws, size_t ws_size,
                              hipStream_t stream) {
  const float* x   = (const float*)d_in[0];
  const float* W1  = (const float*)d_in[1];
  const float* b1  = (const float*)d_in[2];
  const float* W2  = (const float*)d_in[3];
  const float* b2  = (const float*)d_in[4];
  const int* edge  = (const int*)d_in[5];
  const int* batch = (const int*)d_in[6];
  float* out = (float*)d_out;

  char* ws = (char*)d_ws;
  // workspace layout (256-aligned)
  int*   cnt    = (int*)(ws + 0);          // 50000 ints
  int*   cursor = (int*)(ws + 200192);     // 50000 ints
  int*   offs   = (int*)(ws + 400384);     // 50000 ints
  int*   bsum   = (int*)(ws + 600576);     // 256 ints
  float* dinv   = (float*)(ws + 601600);   // 50000 f32
  int*   pooled = (int*)(ws + 801792);     // 128*128 ints
  int2*  sedge  = (int2*)(ws + 867328);    // 1.6M int2 (12.8 MB)
  unsigned short* h  = (unsigned short*)(ws + 13667328); // 50000*128 bf16 (12.8 MB)
  unsigned short* wT = (unsigned short*)(ws + 26467328); // 128*512 bf16 (128 KB)

  init_ws<<<SCAN_BLOCKS, 256, 0, stream>>>(cnt, cursor, pooled);
  count_deg<<<N_EDGES / 256, 256, 0, stream>>>(edge, cnt);
  dinv_kernel<<<SCAN_BLOCKS, 256, 0, stream>>>(cnt, dinv);
  scan1<<<SCAN_BLOCKS, 256, 0, stream>>>(cnt, offs, bsum);
  scan2<<<1, 256, 0, stream>>>(bsum);
  scan3<<<SCAN_BLOCKS, 256, 0, stream>>>(offs, bsum);
  wconv<<<(N_HID * N_FEAT + 255) / 256, 256, 0, stream>>>(W1, wT);
  gemm_mfma<<<(N_WAVES_GEMM + 3) / 4, 256, 0, stream>>>(x, wT, h);
  scatter_edges<<<N_EDGES / 256, 256, 0, stream>>>(edge, dinv, offs, cursor, sedge);
  aggregate_pool<<<N_NODES / 4, 256, 0, stream>>>(h, sedge, dinv, cnt, offs, b1, batch, pooled);
  head_kernel<<<1, 128, 0, stream>>>(pooled, W2, b2, out);
}

// Round 3
// 333.303 us; speedup vs baseline: 1.2089x; 1.1030x over previous
//
#include <hip/hip_runtime.h>

#define N_NODES   50000
#define N_EDGES   1600000
#define N_FEAT    512
#define N_HID     128
#define NUM_GRAPHS 128
#define SCAN_BLOCKS 196       // ceil(50000/256) for simple per-node kernels
#define N_WAVES_GEMM (N_NODES / 16)   // 3125

#define NBUCK 391             // ceil(50000/128) buckets of 128 dst nodes
#define EPB   6400            // edges per bin_edges block (250 blocks)
#define BCAP  5120            // max edges per bucket in LDS (mean 4096, std 64)

typedef short bf16x8 __attribute__((ext_vector_type(8)));
typedef float f32x4  __attribute__((ext_vector_type(4)));

static __device__ __forceinline__ unsigned short f2bf(float f) {
  union { float f; unsigned int u; } v; v.f = f;
  unsigned int u = v.u;
  unsigned int r = (u + 0x7FFFu + ((u >> 16) & 1u)) >> 16;   // RNE
  return (unsigned short)r;
}
static __device__ __forceinline__ float bf2f(unsigned int bits16) {
  union { unsigned int u; float f; } v; v.u = bits16 << 16; return v.f;
}

// ---------------- init: zero cnt / pooled ----------------
__global__ void init_ws(int* __restrict__ cnt, int* __restrict__ pooled) {
  int i = blockIdx.x * 256 + threadIdx.x;
  if (i < N_NODES) cnt[i] = 0;
  if (i < NUM_GRAPHS * N_HID) pooled[i] = 0;
}

// ---------------- degree count over dst ----------------
__global__ void count_deg(const int* __restrict__ edge, int* __restrict__ cnt) {
  int e = blockIdx.x * 256 + threadIdx.x;
  if (e < N_EDGES) atomicAdd(&cnt[edge[N_EDGES + e]], 1);
}

// ---------------- dinv = rsqrt(deg+1) ----------------
__global__ void dinv_kernel(const int* __restrict__ cnt, float* __restrict__ dinv) {
  int i = blockIdx.x * 256 + threadIdx.x;
  if (i < N_NODES) dinv[i] = rsqrtf((float)(cnt[i] + 1));
}

// ---------------- bucket_cnt[b] = sum of cnt over bucket's 128 nodes ----------------
__global__ __launch_bounds__(128) void bucket_sum(const int* __restrict__ cnt,
                                                  int* __restrict__ bucket_cnt) {
  __shared__ int red[128];
  int t = threadIdx.x;
  int node = blockIdx.x * 128 + t;
  red[t] = (node < N_NODES) ? cnt[node] : 0;
  __syncthreads();
  for (int d = 64; d > 0; d >>= 1) {
    if (t < d) red[t] += red[t + d];
    __syncthreads();
  }
  if (t == 0) bucket_cnt[blockIdx.x] = red[0];
}

// ---------------- exclusive scan of bucket_cnt (391 <= 512), 1 block ----------------
__global__ __launch_bounds__(256) void bucket_scan(const int* __restrict__ bucket_cnt,
                                                   int* __restrict__ bucket_base,
                                                   int* __restrict__ gcursor) {
  __shared__ int tsum[256];
  int t = threadIdx.x;
  int i0 = 2 * t, i1 = 2 * t + 1;
  int v0 = (i0 < NBUCK) ? bucket_cnt[i0] : 0;
  int v1 = (i1 < NBUCK) ? bucket_cnt[i1] : 0;
  tsum[t] = v0 + v1;
  __syncthreads();
  for (int d = 1; d < 256; d <<= 1) {
    int add = (t >= d) ? tsum[t - d] : 0;
    __syncthreads();
    tsum[t] += add;
    __syncthreads();
  }
  int excl = tsum[t] - (v0 + v1);
  if (i0 < NBUCK) { bucket_base[i0] = excl;      gcursor[i0] = excl; }
  if (i1 < NBUCK) { bucket_base[i1] = excl + v0; gcursor[i1] = excl + v0; }
}

// ---------------- phase A: bin edges into bucket regions (block-contiguous) -----
// record: x = src | (dst_local << 16)   (src<2^16, dst_local<128), y = w bits
__global__ __launch_bounds__(256) void bin_edges(const int* __restrict__ edge,
                                                 const float* __restrict__ dinv,
                                                 int* __restrict__ gcursor,
                                                 int2* __restrict__ brec) {
  __shared__ int lcnt[NBUCK];
  __shared__ int lbase[NBUCK];
  const int t = threadIdx.x;
  const int e0 = blockIdx.x * EPB;
  for (int b = t; b < NBUCK; b += 256) lcnt[b] = 0;
  __syncthreads();
  // pass 1: count
  for (int e = e0 + t; e < e0 + EPB; e += 256)
    atomicAdd(&lcnt[edge[N_EDGES + e] >> 7], 1);
  __syncthreads();
  // reserve global space per bucket
  for (int b = t; b < NBUCK; b += 256) {
    int c = lcnt[b];
    lbase[b] = c ? atomicAdd(&gcursor[b], c) : 0;
  }
  __syncthreads();
  for (int b = t; b < NBUCK; b += 256) lcnt[b] = 0;   // reuse as cursor
  __syncthreads();
  // pass 2: place
  for (int e = e0 + t; e < e0 + EPB; e += 256) {
    int s = edge[e];
    int d = edge[N_EDGES + e];
    int b = d >> 7;
    int pos = lbase[b] + atomicAdd(&lcnt[b], 1);
    int2 r;
    r.x = s | ((d & 127) << 16);
    r.y = __float_as_int(dinv[s] * dinv[d]);
    brec[pos] = r;
  }
}

// ---------------- phase B: per-bucket LDS counting sort by (dst_local, src>>14) --
// writes final sedge (int2: src, w) node-ordered + offs[node]
__global__ __launch_bounds__(256) void sort_bucket(const int2* __restrict__ brec,
                                                   const int* __restrict__ bucket_base,
                                                   const int* __restrict__ bucket_cnt,
                                                   int2* __restrict__ sedge,
                                                   int* __restrict__ offs) {
  __shared__ int2 recs[BCAP];          // 40 KB
  __shared__ int bcnt[512], boff[512], bcur[512];
  __shared__ int tsum[256];
  const int t = threadIdx.x;
  const int b = blockIdx.x;
  const int base = bucket_base[b];
  int nb = bucket_cnt[b];
  if (nb > BCAP) nb = BCAP;            // safety (never expected)

  for (int i = t; i < nb; i += 256) recs[i] = brec[base + i];
  bcnt[t] = 0; bcnt[t + 256] = 0;
  __syncthreads();
  for (int i = t; i < nb; i += 256) {
    int rx = recs[i].x;
    int key = (((rx >> 16) & 127) << 2) | ((rx & 0xFFFF) >> 14);
    atomicAdd(&bcnt[key], 1);
  }
  __syncthreads();
  // exclusive scan of bcnt[512] with 256 threads
  int v0 = bcnt[2 * t], v1 = bcnt[2 * t + 1];
  tsum[t] = v0 + v1;
  __syncthreads();
  for (int d = 1; d < 256; d <<= 1) {
    int add = (t >= d) ? tsum[t - d] : 0;
    __syncthreads();
    tsum[t] += add;
    __syncthreads();
  }
  int excl = tsum[t] - (v0 + v1);
  boff[2 * t] = excl; boff[2 * t + 1] = excl + v0;
  bcur[2 * t] = excl; bcur[2 * t + 1] = excl + v0;
  __syncthreads();
  // node offs: node = b*128 + t  (t<128)
  if (t < 128) {
    int node = b * 128 + t;
    if (node < N_NODES) offs[node] = base + boff[t << 2];
  }
  // scatter into final position
  for (int i = t; i < nb; i += 256) {
    int2 r = recs[i];
    int key = (((r.x >> 16) & 127) << 2) | ((r.x & 0xFFFF) >> 14);
    int pos = atomicAdd(&bcur[key], 1);
    int2 outr; outr.x = r.x & 0xFFFF; outr.y = r.y;
    sedge[base + pos] = outr;
  }
}

// ---------------- W1 [512][128] fp32 -> wT [128][512] bf16 ----------------
__global__ __launch_bounds__(256) void wconv(const float* __restrict__ W,
                                             unsigned short* __restrict__ wT) {
  int i = blockIdx.x * 256 + threadIdx.x;
  if (i < N_HID * N_FEAT) {
    int n = i >> 9, k = i & 511;
    wT[i] = f2bf(W[(size_t)k * N_HID + n]);
  }
}

// ---------------- GEMM: h(bf16)[N,128] = x[N,512] @ W1 via MFMA bf16 ----------------
__global__ __launch_bounds__(256) void gemm_mfma(const float* __restrict__ x,
                                                 const unsigned short* __restrict__ wT,
                                                 unsigned short* __restrict__ h) {
  const int wave = (blockIdx.x * 256 + threadIdx.x) >> 6;
  if (wave >= N_WAVES_GEMM) return;
  const int lane = threadIdx.x & 63;
  const int row0 = wave * 16;
  const int arow = row0 + (lane & 15);
  const int kbase = (lane >> 4) * 8;

  f32x4 acc[8];
#pragma unroll
  for (int i = 0; i < 8; i++) acc[i] = (f32x4){0.f, 0.f, 0.f, 0.f};

  for (int k0 = 0; k0 < N_FEAT; k0 += 32) {
    const float* ap = x + (size_t)arow * N_FEAT + k0 + kbase;
    float4 a0 = *(const float4*)ap;
    float4 a1 = *(const float4*)(ap + 4);
    bf16x8 af;
    af[0] = (short)f2bf(a0.x); af[1] = (short)f2bf(a0.y);
    af[2] = (short)f2bf(a0.z); af[3] = (short)f2bf(a0.w);
    af[4] = (short)f2bf(a1.x); af[5] = (short)f2bf(a1.y);
    af[6] = (short)f2bf(a1.z); af[7] = (short)f2bf(a1.w);

#pragma unroll
    for (int ct = 0; ct < 8; ct++) {
      const bf16x8 bf = *(const bf16x8*)(wT + (size_t)(ct * 16 + (lane & 15)) * N_FEAT
                                            + k0 + kbase);
      acc[ct] = __builtin_amdgcn_mfma_f32_16x16x32_bf16(af, bf, acc[ct], 0, 0, 0);
    }
  }

#pragma unroll
  for (int ct = 0; ct < 8; ct++) {
#pragma unroll
    for (int r = 0; r < 4; r++) {
      int row = row0 + (lane >> 4) * 4 + r;
      int col = ct * 16 + (lane & 15);
      h[(size_t)row * N_HID + col] = f2bf(acc[ct][r]);
    }
  }
}

// ---------------- aggregation + bias + relu + fused segment-max pool ----------------
// 256 threads = 4 nodes x 64 lanes; lane owns 2 features. 8-deep gather batches
// with next-batch sedge prefetch overlapping the gathers.
__global__ __launch_bounds__(256) void aggregate_pool(
    const unsigned short* __restrict__ h, const int2* __restrict__ sedge,
    const float* __restrict__ dinv, const int* __restrict__ cnt,
    const int* __restrict__ offs, const float* __restrict__ b1,
    const int* __restrict__ batch, int* __restrict__ pooled) {
  int node = blockIdx.x * 4 + (threadIdx.x >> 6);
  int lane = threadIdx.x & 63;
  int f2 = lane * 2;

  float dv = dinv[node];
  unsigned int p = *(const unsigned int*)(h + (size_t)node * N_HID + f2);
  float a0 = bf2f(p & 0xFFFFu) * dv * dv;   // self loop
  float a1 = bf2f(p >> 16) * dv * dv;

  const int base = offs[node];
  const int n = cnt[node];
  const int n8 = n & ~7;
  int2 e[8], en[8];
  if (n8 > 0) {
#pragma unroll
    for (int u = 0; u < 8; u++) e[u] = sedge[base + u];
  }
  for (int j = 0; j < n8; j += 8) {
    unsigned int q[8];
#pragma unroll
    for (int u = 0; u < 8; u++)
      q[u] = *(const unsigned int*)(h + (size_t)e[u].x * N_HID + f2);
    // prefetch next batch (may read past this node's segment; buffer is valid)
#pragma unroll
    for (int u = 0; u < 8; u++) en[u] = sedge[base + j + 8 + u];
#pragma unroll
    for (int u = 0; u < 8; u++) {
      float w = __int_as_float(e[u].y);
      a0 = fmaf(w, bf2f(q[u] & 0xFFFFu), a0);
      a1 = fmaf(w, bf2f(q[u] >> 16), a1);
    }
#pragma unroll
    for (int u = 0; u < 8; u++) e[u] = en[u];
  }
  for (int j = n8; j < n; j++) {
    int2 ew = sedge[base + j];
    float w = __int_as_float(ew.y);
    unsigned int q = *(const unsigned int*)(h + (size_t)ew.x * N_HID + f2);
    a0 = fmaf(w, bf2f(q & 0xFFFFu), a0);
    a1 = fmaf(w, bf2f(q >> 16), a1);
  }

  a0 = fmaxf(a0 + b1[f2], 0.f);
  a1 = fmaxf(a1 + b1[f2 + 1], 0.f);

  int g = batch[node];
  atomicMax(&pooled[g * N_HID + f2],     __float_as_int(a0));
  atomicMax(&pooled[g * N_HID + f2 + 1], __float_as_int(a1));
}

// ---------------- head: logits + log_softmax ----------------
__global__ __launch_bounds__(128) void head_kernel(const int* __restrict__ pooled,
                                                   const float* __restrict__ W2,
                                                   const float* __restrict__ b2,
                                                   float* __restrict__ out) {
  __shared__ float sW[N_HID * 2];
  int t = threadIdx.x;
  sW[t] = W2[t];
  sW[t + 128] = W2[t + 128];
  __syncthreads();
  float l0 = b2[0], l1 = b2[1];
  for (int f = 0; f < N_HID; f++) {
    float pv = __int_as_float(pooled[t * N_HID + f]);
    l0 = fmaf(pv, sW[f * 2 + 0], l0);
    l1 = fmaf(pv, sW[f * 2 + 1], l1);
  }
  float m = fmaxf(l0, l1);
  float lse = m + logf(expf(l0 - m) + expf(l1 - m));
  out[t * 2 + 0] = l0 - lse;
  out[t * 2 + 1] = l1 - lse;
}

extern "C" void kernel_launch(void* const* d_in, const int* in_sizes, int n_in,
                              void* d_out, int out_size, void* d_ws, size_t ws_size,
                              hipStream_t stream) {
  const float* x   = (const float*)d_in[0];
  const float* W1  = (const float*)d_in[1];
  const float* b1  = (const float*)d_in[2];
  const float* W2  = (const float*)d_in[3];
  const float* b2  = (const float*)d_in[4];
  const int* edge  = (const int*)d_in[5];
  const int* batch = (const int*)d_in[6];
  float* out = (float*)d_out;

  char* ws = (char*)d_ws;
  int*   cnt    = (int*)(ws + 0);          // 50000 ints
  int*   offs   = (int*)(ws + 400384);     // 50000 ints
  float* dinv   = (float*)(ws + 601600);   // 50000 f32
  int*   pooled = (int*)(ws + 801792);     // 128*128 ints
  int2*  sedge  = (int2*)(ws + 867328);    // 1.6M int2 (12.8 MB)
  unsigned short* h  = (unsigned short*)(ws + 13667328); // 50000*128 bf16 (12.8 MB)
  int2*  brec   = (int2*)(ws + 13667328);  // aliases h (dead before gemm writes h)
  unsigned short* wT = (unsigned short*)(ws + 26467328); // 128*512 bf16 (128 KB)
  int* bucket_cnt  = (int*)(ws + 26598400);  // 391 ints
  int* bucket_base = (int*)(ws + 26600448);  // 391 ints
  int* gcursor     = (int*)(ws + 26602496);  // 391 ints

  init_ws<<<SCAN_BLOCKS, 256, 0, stream>>>(cnt, pooled);
  count_deg<<<N_EDGES / 256, 256, 0, stream>>>(edge, cnt);
  dinv_kernel<<<SCAN_BLOCKS, 256, 0, stream>>>(cnt, dinv);
  bucket_sum<<<NBUCK, 128, 0, stream>>>(cnt, bucket_cnt);
  bucket_scan<<<1, 256, 0, stream>>>(bucket_cnt, bucket_base, gcursor);
  bin_edges<<<N_EDGES / EPB, 256, 0, stream>>>(edge, dinv, gcursor, brec);
  sort_bucket<<<NBUCK, 256, 0, stream>>>(brec, bucket_base, bucket_cnt, sedge, offs);
  wconv<<<(N_HID * N_FEAT + 255) / 256, 256, 0, stream>>>(W1, wT);
  gemm_mfma<<<(N_WAVES_GEMM + 3) / 4, 256, 0, stream>>>(x, wT, h);
  aggregate_pool<<<N_NODES / 4, 256, 0, stream>>>(h, sedge, dinv, cnt, offs, b1, batch, pooled);
  head_kernel<<<1, 128, 0, stream>>>(pooled, W2, b2, out);
}

// Round 4
// 245.292 us; speedup vs baseline: 1.6427x; 1.3588x over previous
//
#include <hip/hip_runtime.h>

#define N_NODES   50000
#define N_EDGES   1600000
#define N_FEAT    512
#define N_HID     128
#define NUM_GRAPHS 128
#define N_WAVES_GEMM 3125     // 50000/16 rows per wave

#define NBUCK 391             // ceil(50000/128)
#define EPB   6400            // edges per bin block
#define BCAP  5120            // bucket capacity in LDS (mean 4092, sigma ~64)
#define BIN_BLOCKS  250       // N_EDGES / EPB
#define GEMM_BLOCKS 782       // ceil(3125/4)
#define PREP_DINV_BLOCKS 196  // ceil(50000/256)

typedef short bf16x8 __attribute__((ext_vector_type(8)));
typedef float f32x4  __attribute__((ext_vector_type(4)));

static __device__ __forceinline__ unsigned short f2bf(float f) {
  union { float f; unsigned int u; } v; v.f = f;
  unsigned int u = v.u;
  unsigned int r = (u + 0x7FFFu + ((u >> 16) & 1u)) >> 16;   // RNE
  return (unsigned short)r;
}
static __device__ __forceinline__ float bf2f(unsigned int bits16) {
  union { unsigned int u; float f; } v; v.u = bits16 << 16; return v.f;
}

// ---------------- init: zero cnt / pooled ----------------
__global__ void init_ws(int* __restrict__ cnt, int* __restrict__ pooled) {
  int i = blockIdx.x * 256 + threadIdx.x;
  if (i < N_NODES) cnt[i] = 0;
  if (i < NUM_GRAPHS * N_HID) pooled[i] = 0;
}

// ---------------- degree count over dst ----------------
__global__ void count_deg(const int* __restrict__ edge, int* __restrict__ cnt) {
  int e = blockIdx.x * 256 + threadIdx.x;
  if (e < N_EDGES) atomicAdd(&cnt[edge[N_EDGES + e]], 1);
}

// ------- prep: dinv + bucket sums (blocks 0..195) | wconv (blocks 196..451) -------
__global__ __launch_bounds__(256) void prep(const int* __restrict__ cnt,
                                            float* __restrict__ dinv,
                                            int* __restrict__ bucket_cnt,
                                            const float* __restrict__ W,
                                            unsigned short* __restrict__ wT) {
  if (blockIdx.x < PREP_DINV_BLOCKS) {
    __shared__ int red[256];
    int t = threadIdx.x;
    int node = blockIdx.x * 256 + t;
    int c = 0;
    if (node < N_NODES) {
      c = cnt[node];
      dinv[node] = rsqrtf((float)(c + 1));
    }
    red[t] = c;
    __syncthreads();
    for (int d = 64; d > 0; d >>= 1) {
      if ((t & 127) < d) red[t] += red[t + d];
      __syncthreads();
    }
    int b2 = blockIdx.x * 2;
    if (t == 0) bucket_cnt[b2] = red[0];
    if (t == 128 && b2 + 1 < NBUCK) bucket_cnt[b2 + 1] = red[128];
  } else {
    int i = (blockIdx.x - PREP_DINV_BLOCKS) * 256 + threadIdx.x;
    if (i < N_HID * N_FEAT) {
      int n = i >> 9, k = i & 511;
      wT[i] = f2bf(W[(size_t)k * N_HID + n]);
    }
  }
}

// ---------------- exclusive scan of bucket_cnt (391 <= 512), 1 block ----------------
__global__ __launch_bounds__(256) void bucket_scan(const int* __restrict__ bucket_cnt,
                                                   int* __restrict__ bucket_base,
                                                   int* __restrict__ gcursor) {
  __shared__ int tsum[256];
  int t = threadIdx.x;
  int i0 = 2 * t, i1 = 2 * t + 1;
  int v0 = (i0 < NBUCK) ? bucket_cnt[i0] : 0;
  int v1 = (i1 < NBUCK) ? bucket_cnt[i1] : 0;
  tsum[t] = v0 + v1;
  __syncthreads();
  for (int d = 1; d < 256; d <<= 1) {
    int add = (t >= d) ? tsum[t - d] : 0;
    __syncthreads();
    tsum[t] += add;
    __syncthreads();
  }
  int excl = tsum[t] - (v0 + v1);
  if (i0 < NBUCK) { bucket_base[i0] = excl;      gcursor[i0] = excl; }
  if (i1 < NBUCK) { bucket_base[i1] = excl + v0; gcursor[i1] = excl + v0; }
}

// -------- fused: bin_edges (blocks 0..249) | gemm h' = dinv*(x@W1) (blocks 250+) ---
// bin record: src | (dst_local << 16)  (single int)
__global__ __launch_bounds__(256) void gemm_bin(const int* __restrict__ edge,
                                                int* __restrict__ gcursor,
                                                int* __restrict__ brec,
                                                const float* __restrict__ x,
                                                const unsigned short* __restrict__ wT,
                                                const float* __restrict__ dinv,
                                                unsigned short* __restrict__ h) {
  if (blockIdx.x < BIN_BLOCKS) {
    __shared__ int lcnt[NBUCK];
    __shared__ int lbase[NBUCK];
    const int t = threadIdx.x;
    const int e0 = blockIdx.x * EPB;
    for (int b = t; b < NBUCK; b += 256) lcnt[b] = 0;
    __syncthreads();
    for (int e = e0 + t; e < e0 + EPB; e += 256)
      atomicAdd(&lcnt[edge[N_EDGES + e] >> 7], 1);
    __syncthreads();
    for (int b = t; b < NBUCK; b += 256) {
      int c = lcnt[b];
      lbase[b] = c ? atomicAdd(&gcursor[b], c) : 0;
    }
    __syncthreads();
    for (int b = t; b < NBUCK; b += 256) lcnt[b] = 0;   // reuse as cursor
    __syncthreads();
    for (int e = e0 + t; e < e0 + EPB; e += 256) {
      int s = edge[e];
      int d = edge[N_EDGES + e];
      int b = d >> 7;
      int pos = lbase[b] + atomicAdd(&lcnt[b], 1);
      brec[pos] = s | ((d & 127) << 16);
    }
  } else {
    const int wave = ((blockIdx.x - BIN_BLOCKS) * 256 + threadIdx.x) >> 6;
    if (wave >= N_WAVES_GEMM) return;
    const int lane = threadIdx.x & 63;
    const int row0 = wave * 16;
    const int arow = row0 + (lane & 15);
    const int kbase = (lane >> 4) * 8;

    f32x4 acc[8];
#pragma unroll
    for (int i = 0; i < 8; i++) acc[i] = (f32x4){0.f, 0.f, 0.f, 0.f};

    for (int k0 = 0; k0 < N_FEAT; k0 += 32) {
      const float* ap = x + (size_t)arow * N_FEAT + k0 + kbase;
      float4 a0 = *(const float4*)ap;
      float4 a1 = *(const float4*)(ap + 4);
      bf16x8 af;
      af[0] = (short)f2bf(a0.x); af[1] = (short)f2bf(a0.y);
      af[2] = (short)f2bf(a0.z); af[3] = (short)f2bf(a0.w);
      af[4] = (short)f2bf(a1.x); af[5] = (short)f2bf(a1.y);
      af[6] = (short)f2bf(a1.z); af[7] = (short)f2bf(a1.w);

#pragma unroll
      for (int ct = 0; ct < 8; ct++) {
        const bf16x8 bf = *(const bf16x8*)(wT + (size_t)(ct * 16 + (lane & 15)) * N_FEAT
                                              + k0 + kbase);
        acc[ct] = __builtin_amdgcn_mfma_f32_16x16x32_bf16(af, bf, acc[ct], 0, 0, 0);
      }
    }

    // epilogue: h'[row] = bf16(dinv[row] * acc)
    float dvv[4];
#pragma unroll
    for (int r = 0; r < 4; r++) dvv[r] = dinv[row0 + (lane >> 4) * 4 + r];
#pragma unroll
    for (int ct = 0; ct < 8; ct++) {
#pragma unroll
      for (int r = 0; r < 4; r++) {
        int row = row0 + (lane >> 4) * 4 + r;
        int col = ct * 16 + (lane & 15);
        h[(size_t)row * N_HID + col] = f2bf(acc[ct][r] * dvv[r]);
      }
    }
  }
}

// -------- per-bucket LDS counting sort by (dst_local, src>>14); emits sedge+offs ---
__global__ __launch_bounds__(256) void sort_bucket(const int* __restrict__ brec,
                                                   const int* __restrict__ bucket_base,
                                                   const int* __restrict__ bucket_cnt,
                                                   int* __restrict__ sedge,
                                                   int* __restrict__ offs) {
  __shared__ int recs[BCAP];           // 20 KB
  __shared__ int bcnt[512], boff[512], bcur[512];
  __shared__ int tsum[256];
  const int t = threadIdx.x;
  const int b = blockIdx.x;
  const int base = bucket_base[b];
  int nb = bucket_cnt[b];
  if (nb > BCAP) nb = BCAP;            // safety

  for (int i = t; i < nb; i += 256) recs[i] = brec[base + i];
  bcnt[t] = 0; bcnt[t + 256] = 0;
  __syncthreads();
  for (int i = t; i < nb; i += 256) {
    int rx = recs[i];
    int key = (((rx >> 16) & 127) << 2) | ((rx & 0xFFFF) >> 14);
    atomicAdd(&bcnt[key], 1);
  }
  __syncthreads();
  int v0 = bcnt[2 * t], v1 = bcnt[2 * t + 1];
  tsum[t] = v0 + v1;
  __syncthreads();
  for (int d = 1; d < 256; d <<= 1) {
    int add = (t >= d) ? tsum[t - d] : 0;
    __syncthreads();
    tsum[t] += add;
    __syncthreads();
  }
  int excl = tsum[t] - (v0 + v1);
  boff[2 * t] = excl; boff[2 * t + 1] = excl + v0;
  bcur[2 * t] = excl; bcur[2 * t + 1] = excl + v0;
  __syncthreads();
  if (t < 128) {
    int node = b * 128 + t;
    if (node < N_NODES) offs[node] = base + boff[t << 2];
  }
  for (int i = t; i < nb; i += 256) {
    int r = recs[i];
    int key = (((r >> 16) & 127) << 2) | ((r & 0xFFFF) >> 14);
    int pos = atomicAdd(&bcur[key], 1);
    sedge[base + pos] = r & 0xFFFF;
  }
}

// ------ aggregation + scale + bias + relu + LDS-reduced segment-max pool ------
// 512 threads = 8 nodes x 64 lanes; lane owns 2 features.
__global__ __launch_bounds__(512) void aggregate_pool(
    const unsigned short* __restrict__ h, const int* __restrict__ sedge,
    const float* __restrict__ dinv, const int* __restrict__ cnt,
    const int* __restrict__ offs, const float* __restrict__ b1,
    const int* __restrict__ batch, int* __restrict__ pooled) {
  __shared__ float vsh[8][128];
  __shared__ int gsh[8];
  const int wv = threadIdx.x >> 6;
  const int lane = threadIdx.x & 63;
  const int node = blockIdx.x * 8 + wv;       // 6250*8 == 50000 exactly
  const int f2 = lane * 2;

  unsigned int p = *(const unsigned int*)(h + (size_t)node * N_HID + f2);
  float a0 = bf2f(p & 0xFFFFu);               // self loop (h' has dinv[src] folded)
  float a1 = bf2f(p >> 16);

  const int base = offs[node];
  const int n = cnt[node];
  const int n8 = n & ~7;
  int s[8], sn[8];
  if (n8 > 0) {
#pragma unroll
    for (int u = 0; u < 8; u++) s[u] = sedge[base + u];
  }
  for (int j = 0; j < n8; j += 8) {
    unsigned int q[8];
#pragma unroll
    for (int u = 0; u < 8; u++)
      q[u] = *(const unsigned int*)(h + (size_t)s[u] * N_HID + f2);
#pragma unroll
    for (int u = 0; u < 8; u++) sn[u] = sedge[base + j + 8 + u];  // prefetch (safe region)
#pragma unroll
    for (int u = 0; u < 8; u++) { a0 += bf2f(q[u] & 0xFFFFu); a1 += bf2f(q[u] >> 16); }
#pragma unroll
    for (int u = 0; u < 8; u++) s[u] = sn[u];
  }
  for (int j = n8; j < n; j++) {
    int sv = sedge[base + j];
    unsigned int q = *(const unsigned int*)(h + (size_t)sv * N_HID + f2);
    a0 += bf2f(q & 0xFFFFu); a1 += bf2f(q >> 16);
  }

  float dv = dinv[node];
  a0 = fmaxf(fmaf(a0, dv, b1[f2]), 0.f);
  a1 = fmaxf(fmaf(a1, dv, b1[f2 + 1]), 0.f);

  int g = batch[node];
  if (lane == 0) gsh[wv] = g;
  vsh[wv][f2] = a0; vsh[wv][f2 + 1] = a1;
  __syncthreads();
  int gprev = (wv > 0) ? gsh[wv - 1] : -1;
  if (g != gprev) {                           // leader wave for this graph-run
    float m0 = a0, m1 = a1;
    for (int r = wv + 1; r < 8 && gsh[r] == g; r++) {
      m0 = fmaxf(m0, vsh[r][f2]); m1 = fmaxf(m1, vsh[r][f2 + 1]);
    }
    atomicMax(&pooled[g * N_HID + f2],     __float_as_int(m0));
    atomicMax(&pooled[g * N_HID + f2 + 1], __float_as_int(m1));
  }
}

// ---------------- head: logits + log_softmax ----------------
__global__ __launch_bounds__(128) void head_kernel(const int* __restrict__ pooled,
                                                   const float* __restrict__ W2,
                                                   const float* __restrict__ b2,
                                                   float* __restrict__ out) {
  __shared__ float sW[N_HID * 2];
  int t = threadIdx.x;
  sW[t] = W2[t];
  sW[t + 128] = W2[t + 128];
  __syncthreads();
  float l0 = b2[0], l1 = b2[1];
  for (int f = 0; f < N_HID; f++) {
    float pv = __int_as_float(pooled[t * N_HID + f]);
    l0 = fmaf(pv, sW[f * 2 + 0], l0);
    l1 = fmaf(pv, sW[f * 2 + 1], l1);
  }
  float m = fmaxf(l0, l1);
  float lse = m + logf(expf(l0 - m) + expf(l1 - m));
  out[t * 2 + 0] = l0 - lse;
  out[t * 2 + 1] = l1 - lse;
}

extern "C" void kernel_launch(void* const* d_in, const int* in_sizes, int n_in,
                              void* d_out, int out_size, void* d_ws, size_t ws_size,
                              hipStream_t stream) {
  const float* x   = (const float*)d_in[0];
  const float* W1  = (const float*)d_in[1];
  const float* b1  = (const float*)d_in[2];
  const float* W2  = (const float*)d_in[3];
  const float* b2  = (const float*)d_in[4];
  const int* edge  = (const int*)d_in[5];
  const int* batch = (const int*)d_in[6];
  float* out = (float*)d_out;

  char* ws = (char*)d_ws;
  int*   cnt         = (int*)(ws + 0);          // 200 KB
  int*   offs        = (int*)(ws + 200704);     // 200 KB
  float* dinv        = (float*)(ws + 401408);   // 200 KB
  int*   pooled      = (int*)(ws + 602112);     // 64 KB
  int*   bucket_cnt  = (int*)(ws + 667648);     // 2 KB
  int*   bucket_base = (int*)(ws + 669696);     // 2 KB
  int*   gcursor     = (int*)(ws + 671744);     // 2 KB
  int*   sedge       = (int*)(ws + 673792);     // 6.4 MB
  int*   brec        = (int*)(ws + 7073792);    // 6.4 MB
  unsigned short* h  = (unsigned short*)(ws + 13473792); // 12.8 MB
  unsigned short* wT = (unsigned short*)(ws + 26273792); // 128 KB

  init_ws<<<196, 256, 0, stream>>>(cnt, pooled);
  count_deg<<<N_EDGES / 256, 256, 0, stream>>>(edge, cnt);
  prep<<<PREP_DINV_BLOCKS + 256, 256, 0, stream>>>(cnt, dinv, bucket_cnt, W1, wT);
  bucket_scan<<<1, 256, 0, stream>>>(bucket_cnt, bucket_base, gcursor);
  gemm_bin<<<BIN_BLOCKS + GEMM_BLOCKS, 256, 0, stream>>>(edge, gcursor, brec, x, wT, dinv, h);
  sort_bucket<<<NBUCK, 256, 0, stream>>>(brec, bucket_base, bucket_cnt, sedge, offs);
  aggregate_pool<<<N_NODES / 8, 512, 0, stream>>>(h, sedge, dinv, cnt, offs, b1, batch, pooled);
  head_kernel<<<1, 128, 0, stream>>>(pooled, W2, b2, out);
}